// Round 10
// baseline (145.723 us; speedup 1.0000x reference)
//
#include <hip/hip_runtime.h>
#include <math.h>

#define Bb 2
#define Ll 2048
#define Dm 1024
#define Ns 16
#define Rr 64
#define Ee 96          // DT_RANK + 2*D_STATE
#define XPS 8          // K-splits for xproj GEMM (K-slice = 128)
#define BLK (Bb*Ll)    // 4096 rows
#define NTHR 256
#define LOG2E 1.4426950408889634f
#define LN2   0.6931471805599453f

typedef __attribute__((ext_vector_type(8))) short bf16x8;
typedef __attribute__((ext_vector_type(4))) float f32x4;

__device__ inline float ex2(float x) {
#if __has_builtin(__builtin_amdgcn_exp2f)
    return __builtin_amdgcn_exp2f(x);
#else
    return exp2f(x);
#endif
}
__device__ inline float lg2(float x) {
#if __has_builtin(__builtin_amdgcn_logf)
    return __builtin_amdgcn_logf(x);
#else
    return log2f(x);
#endif
}
__device__ inline float softplus_f(float z) {
    float e = ex2(-fabsf(z) * LOG2E);
    return fmaxf(z, 0.f) + lg2(1.f + e) * LN2;
}

// f32 -> bf16 with round-to-nearest-even
__device__ inline unsigned short f2bf(float f) {
    union { float f; unsigned u; } v; v.f = f;
    unsigned u = v.u + 0x7fffu + ((v.u >> 16) & 1u);
    return (unsigned short)(u >> 16);
}
__device__ inline uint2 pack4(float a, float b, float c, float d) {
    unsigned u0 = ((unsigned)f2bf(b) << 16) | f2bf(a);
    unsigned u1 = ((unsigned)f2bf(d) << 16) | f2bf(c);
    return make_uint2(u0, u1);
}

// ========== Kernel 1: xp_part[ks][bl][e]  (bf16 MFMA; R9 verbatim) ==========
__global__ void __launch_bounds__(NTHR, 4)
k_xproj(const float* __restrict__ x, const float* __restrict__ xw,
        float* __restrict__ xp_part) {
    __shared__ __align__(16) short sm[16*128 + 96*128];   // A | B ; f32 reduce alias
    int tid = threadIdx.x, lane = tid & 63, wid = tid >> 6;
    int bx = blockIdx.x;
    int ks = bx & 7, mt = bx >> 3;
    int i0 = mt * 16;
    int kb = ks * 128;
    short* sA = sm;
    short* sB = sm + 16*128;

#pragma unroll
    for (int i = 0; i < 2; ++i) {
        int idx = tid + i * 256;
        int r = idx >> 5, c4 = idx & 31;
        float4 v = *(const float4*)(x + (size_t)(i0 + r) * Dm + kb + c4 * 4);
        int unit = (c4 >> 1) ^ (r & 7);
        *(uint2*)(sA + r * 128 + unit * 8 + (c4 & 1) * 4) = pack4(v.x, v.y, v.z, v.w);
    }
#pragma unroll
    for (int i = 0; i < 12; ++i) {
        int idx = tid + i * 256;
        int r = idx >> 5, c4 = idx & 31;
        float4 v = *(const float4*)(xw + (size_t)r * Dm + kb + c4 * 4);
        int unit = (c4 >> 1) ^ (r & 7);
        *(uint2*)(sB + r * 128 + unit * 8 + (c4 & 1) * 4) = pack4(v.x, v.y, v.z, v.w);
    }
    __syncthreads();

    f32x4 acc[6];
#pragma unroll
    for (int t = 0; t < 6; ++t) acc[t] = (f32x4)0.f;
    int ra = lane & 15;
    int g = wid * 4 + (lane >> 4);                 // 0..15
    bf16x8 a = *(bf16x8*)(sA + ra * 128 + ((g ^ (ra & 7)) << 3));
#pragma unroll
    for (int nt = 0; nt < 6; ++nt) {
        int br = nt * 16 + (lane & 15);
        bf16x8 b = *(bf16x8*)(sB + br * 128 + ((g ^ (br & 7)) << 3));
        acc[nt] = __builtin_amdgcn_mfma_f32_16x16x32_bf16(a, b, acc[nt], 0, 0, 0);
    }
    __syncthreads();

    float* rp = (float*)sm;
#pragma unroll
    for (int nt = 0; nt < 6; ++nt)
#pragma unroll
        for (int j = 0; j < 4; ++j) {
            int r = ((lane >> 4) << 2) + j;
            int c = nt * 16 + (lane & 15);
            rp[wid * 1536 + r * 96 + c] = acc[nt][j];
        }
    __syncthreads();
#pragma unroll
    for (int o = 0; o < 6; ++o) {
        int idx = o * 256 + tid;
        float s = rp[idx] + rp[1536 + idx] + rp[3072 + idx] + rp[4608 + idx];
        int r = idx / 96, c = idx - r * 96;
        xp_part[((size_t)ks * BLK + (i0 + r)) * Ee + c] = s;
    }
}

// ========== Kernel 2: reduce K-splits -> xp (verbatim) ==========
__global__ void __launch_bounds__(NTHR)
k_prep(const float* __restrict__ xp_part, float* __restrict__ xp) {
    int g = blockIdx.x * NTHR + threadIdx.x;    // 98304 float4s
    const float4* p = (const float4*)xp_part;
    float4 s = p[g];
#pragma unroll
    for (int i = 1; i < XPS; ++i) {
        float4 v = p[(size_t)i * (BLK * Ee / 4) + g];
        s.x += v.x; s.y += v.y; s.z += v.z; s.w += v.w;
    }
    ((float4*)xp)[g] = s;
}

// ========== Kernel 3: delta = softplus(xp[:, :64] . dtw^T + dtb)  (bf16 MFMA; R9 verbatim) ==========
__global__ void __launch_bounds__(NTHR)
k_delta(const float* __restrict__ xp, const float* __restrict__ dtw,
        const float* __restrict__ dtb, float* __restrict__ delta) {
    __shared__ __align__(16) short sA[128 * 64];
    __shared__ __align__(16) short sB[64 * 64];
    int tid = threadIdx.x, lane = tid & 63, wid = tid >> 6;
    int nt16 = blockIdx.x & 15, mt = blockIdx.x >> 4;
    int i0 = mt * 128, j0 = nt16 * 64;

#pragma unroll
    for (int i = 0; i < 8; ++i) {
        int idx = tid + i * 256;
        int r = idx >> 4, c4 = idx & 15;
        float4 v = *(const float4*)(xp + (size_t)(i0 + r) * Ee + c4 * 4);
        int unit = (c4 >> 1) ^ (r & 7);
        *(uint2*)(sA + r * 64 + unit * 8 + (c4 & 1) * 4) = pack4(v.x, v.y, v.z, v.w);
    }
#pragma unroll
    for (int i = 0; i < 4; ++i) {
        int idx = tid + i * 256;
        int r = idx >> 4, c4 = idx & 15;
        float4 v = *(const float4*)(dtw + (size_t)(j0 + r) * Rr + c4 * 4);
        int unit = (c4 >> 1) ^ (r & 7);
        *(uint2*)(sB + r * 64 + unit * 8 + (c4 & 1) * 4) = pack4(v.x, v.y, v.z, v.w);
    }
    __syncthreads();

    f32x4 acc[2][4];
#pragma unroll
    for (int m = 0; m < 2; ++m)
#pragma unroll
        for (int nt = 0; nt < 4; ++nt) acc[m][nt] = (f32x4)0.f;
    int R = wid * 32;
    int r0 = R + (lane & 15), r1 = R + 16 + (lane & 15);
#pragma unroll
    for (int ks = 0; ks < 2; ++ks) {
        int g = ks * 4 + (lane >> 4);
        bf16x8 a0 = *(bf16x8*)(sA + r0 * 64 + ((g ^ (r0 & 7)) << 3));
        bf16x8 a1 = *(bf16x8*)(sA + r1 * 64 + ((g ^ (r1 & 7)) << 3));
#pragma unroll
        for (int nt = 0; nt < 4; ++nt) {
            int br = nt * 16 + (lane & 15);
            bf16x8 b = *(bf16x8*)(sB + br * 64 + ((g ^ (br & 7)) << 3));
            acc[0][nt] = __builtin_amdgcn_mfma_f32_16x16x32_bf16(a0, b, acc[0][nt], 0, 0, 0);
            acc[1][nt] = __builtin_amdgcn_mfma_f32_16x16x32_bf16(a1, b, acc[1][nt], 0, 0, 0);
        }
    }
#pragma unroll
    for (int nt = 0; nt < 4; ++nt) {
        int col = j0 + nt * 16 + (lane & 15);
        float bias = dtb[col];
#pragma unroll
        for (int m = 0; m < 2; ++m)
#pragma unroll
            for (int j = 0; j < 4; ++j) {
                int row = i0 + R + m * 16 + ((lane >> 4) << 2) + j;
                delta[(size_t)row * Dm + col] = softplus_f(acc[m][nt][j] + bias);
            }
    }
}

// ---- helper: load A row, pre-scaled by log2(e), into regs ----
__device__ inline void load_a2(const float* __restrict__ A_log, int d, float* a2) {
    const float4* Ap = (const float4*)(A_log + (size_t)d * Ns);
    float4 a0 = Ap[0], a1 = Ap[1], a2v = Ap[2], a3 = Ap[3];
    float tmp[Ns] = {a0.x,a0.y,a0.z,a0.w, a1.x,a1.y,a1.z,a1.w,
                     a2v.x,a2v.y,a2v.z,a2v.w, a3.x,a3.y,a3.z,a3.w};
#pragma unroll
    for (int n = 0; n < Ns; ++n) a2[n] = -__expf(tmp[n]) * LOG2E;
}

// ========== Kernel 4: DUAL-chunk local scan (h0=0) -> Ec, Sc ==========
// CH=128 (CLv=16); each block handles 2 adjacent chunks over 256 d-columns:
// two independent recurrences per thread double the loads/exp2/fma in flight.
// B rows (32 x 16 floats) staged in LDS, uniform broadcast reads in the loop.
template<int CHv>
__global__ void __launch_bounds__(NTHR)
k_scan_part(const float* __restrict__ delta, const float* __restrict__ x,
            const float* __restrict__ xp, const float* __restrict__ A_log,
            float* __restrict__ Ec, float* __restrict__ Sc) {
    constexpr int CLv = Ll / CHv;            // 16
    constexpr int NP = CHv / 2;              // 64 chunk-pairs per batch
    __shared__ __align__(16) float bsh[2 * CLv * 16];   // 2 KB
    int bx = blockIdx.x;
    int dblk = bx & 3, cp = (bx >> 2) & (NP - 1), b = bx >> 2 >> __builtin_ctz(NP);
    int tid = threadIdx.x;
    int d = dblk * 256 + tid;
    int row0 = b * Ll + cp * (2 * CLv);

    if (tid < 2 * CLv * 4) {                 // 32 rows x 16 floats = 128 float4
        int r = tid >> 2, c = (tid & 3) * 4;
        *(float4*)(bsh + r*16 + c) =
            *(const float4*)(xp + (size_t)(row0 + r) * Ee + Rr + c);
    }
    float a2[Ns];
    load_a2(A_log, d, a2);
    __syncthreads();

    float h0[Ns], h1[Ns];
#pragma unroll
    for (int n = 0; n < Ns; ++n) { h0[n] = 0.f; h1[n] = 0.f; }
    float sd0 = 0.f, sd1 = 0.f;

#pragma unroll 4
    for (int t = 0; t < CLv; ++t) {
        size_t rA = (size_t)(row0 + t);
        size_t rB = (size_t)(row0 + CLv + t);
        float dl0 = delta[rA * Dm + d], xv0 = x[rA * Dm + d];
        float dl1 = delta[rB * Dm + d], xv1 = x[rB * Dm + d];
        const float* b0 = bsh + t * 16;
        const float* b1 = bsh + (CLv + t) * 16;
        float dx0 = dl0 * xv0, dx1 = dl1 * xv1;
        sd0 += dl0; sd1 += dl1;
#pragma unroll
        for (int n = 0; n < Ns; ++n) {
            h0[n] = fmaf(ex2(dl0 * a2[n]), h0[n], dx0 * b0[n]);
            h1[n] = fmaf(ex2(dl1 * a2[n]), h1[n], dx1 * b1[n]);
        }
    }
    size_t base0 = ((size_t)b * CHv + 2 * cp) * Dm + d;
    size_t base1 = base0 + Dm;
    float4* E0 = (float4*)(Ec + base0 * Ns);
    float4* E1 = (float4*)(Ec + base1 * Ns);
    E0[0] = make_float4(h0[0],h0[1],h0[2],h0[3]);   E0[1] = make_float4(h0[4],h0[5],h0[6],h0[7]);
    E0[2] = make_float4(h0[8],h0[9],h0[10],h0[11]); E0[3] = make_float4(h0[12],h0[13],h0[14],h0[15]);
    E1[0] = make_float4(h1[0],h1[1],h1[2],h1[3]);   E1[1] = make_float4(h1[4],h1[5],h1[6],h1[7]);
    E1[2] = make_float4(h1[8],h1[9],h1[10],h1[11]); E1[3] = make_float4(h1[12],h1[13],h1[14],h1[15]);
    Sc[base0] = sd0;
    Sc[base1] = sd1;
}

// ========== Kernel 5a: within-group combine (R1 CH=128 verbatim) ==========
template<int CHv, int G>
__global__ void __launch_bounds__(NTHR)
k_comb1(const float* __restrict__ Ec, const float* __restrict__ Sc,
        const float* __restrict__ A_log, float* __restrict__ Hloc,
        float* __restrict__ Spre, float* __restrict__ Eg, float* __restrict__ Sg) {
    constexpr int CPG = CHv / G;
    int gid = blockIdx.x * NTHR + threadIdx.x;   // Bb*G*Dm*Ns = 262144
    int n = gid & (Ns - 1);
    int d = (gid >> 4) & (Dm - 1);
    int g = (gid >> 14) & (G - 1);
    int b = gid >> 17;
    float a2 = -__expf(A_log[d * Ns + n]) * LOG2E;
    float h = 0.f, S = 0.f;
#pragma unroll
    for (int j = 0; j < CPG; ++j) {
        size_t base = ((size_t)b * CHv + g * CPG + j) * Dm + d;
        float e  = Ec[base * Ns + n];
        float sc = Sc[base];
        Hloc[base * Ns + n] = h;
        if (n == 0) Spre[base] = S;
        h = fmaf(ex2(a2 * sc), h, e);
        S += sc;
    }
    size_t gb = ((size_t)b * G + g) * Dm + d;
    Eg[gb * Ns + n] = h;
    if (n == 0) Sg[gb] = S;
}

// ========== Kernel 5b: across-group combine (verbatim) ==========
template<int G>
__global__ void __launch_bounds__(NTHR)
k_comb2(const float* __restrict__ Eg, const float* __restrict__ Sg,
        const float* __restrict__ A_log, float* __restrict__ Hg) {
    int gid = blockIdx.x * NTHR + threadIdx.x;   // Bb*Dm*Ns = 32768
    int n = gid & (Ns - 1);
    int d = (gid >> 4) & (Dm - 1);
    int b = gid >> 14;
    float a2 = -__expf(A_log[d * Ns + n]) * LOG2E;
    float h = 0.f;
#pragma unroll
    for (int g = 0; g < G; ++g) {
        size_t gb = ((size_t)b * G + g) * Dm + d;
        Hg[gb * Ns + n] = h;
        h = fmaf(ex2(a2 * Sg[gb]), h, Eg[gb * Ns + n]);
    }
}

// ========== Kernel 6: DUAL-chunk full scan; h_in = Hloc + exp2(a2*Spre)*Hg ==========
template<int CHv, int G>
__global__ void __launch_bounds__(NTHR)
k_scan_full(const float* __restrict__ delta, const float* __restrict__ x,
            const float* __restrict__ xp, const float* __restrict__ A_log,
            const float* __restrict__ Dp, const float* __restrict__ Hloc,
            const float* __restrict__ Spre, const float* __restrict__ Hg,
            float* __restrict__ out) {
    constexpr int CLv = Ll / CHv;            // 16
    constexpr int NP = CHv / 2;              // 64
    constexpr int CPG = CHv / G;             // 16
    __shared__ __align__(16) float bcs[2 * CLv * 32];   // 4 KB (B+C for 32 rows)
    int bx = blockIdx.x;
    int dblk = bx & 3, cp = (bx >> 2) & (NP - 1), b = bx >> 2 >> __builtin_ctz(NP);
    int tid = threadIdx.x;
    int d = dblk * 256 + tid;
    int row0 = b * Ll + cp * (2 * CLv);

    {                                        // 32 rows x 32 floats = 256 float4
        int r = tid >> 3, c = (tid & 7) * 4;
        *(float4*)(bcs + r*32 + c) =
            *(const float4*)(xp + (size_t)(row0 + r) * Ee + Rr + c);
    }
    float a2[Ns];
    load_a2(A_log, d, a2);
    int c0 = 2 * cp;
    size_t base0 = ((size_t)b * CHv + c0) * Dm + d;
    size_t base1 = base0 + Dm;
    size_t gb    = ((size_t)b * G + c0 / CPG) * Dm + d;

    float h0[Ns], h1[Ns];
    {
        float sp0 = Spre[base0], sp1 = Spre[base1];
        const float4* Hl0 = (const float4*)(Hloc + base0 * Ns);
        const float4* Hl1 = (const float4*)(Hloc + base1 * Ns);
        const float4* Hp  = (const float4*)(Hg + gb * Ns);
        float4 l0a = Hl0[0], l0b = Hl0[1], l0c = Hl0[2], l0d = Hl0[3];
        float4 l1a = Hl1[0], l1b = Hl1[1], l1c = Hl1[2], l1d = Hl1[3];
        float4 g0a = Hp[0],  g0b = Hp[1],  g0c = Hp[2],  g0d = Hp[3];
        float lv0[Ns] = {l0a.x,l0a.y,l0a.z,l0a.w, l0b.x,l0b.y,l0b.z,l0b.w,
                         l0c.x,l0c.y,l0c.z,l0c.w, l0d.x,l0d.y,l0d.z,l0d.w};
        float lv1[Ns] = {l1a.x,l1a.y,l1a.z,l1a.w, l1b.x,l1b.y,l1b.z,l1b.w,
                         l1c.x,l1c.y,l1c.z,l1c.w, l1d.x,l1d.y,l1d.z,l1d.w};
        float gv[Ns]  = {g0a.x,g0a.y,g0a.z,g0a.w, g0b.x,g0b.y,g0b.z,g0b.w,
                         g0c.x,g0c.y,g0c.z,g0c.w, g0d.x,g0d.y,g0d.z,g0d.w};
#pragma unroll
        for (int n = 0; n < Ns; ++n) {
            h0[n] = fmaf(ex2(a2[n] * sp0), gv[n], lv0[n]);
            h1[n] = fmaf(ex2(a2[n] * sp1), gv[n], lv1[n]);
        }
    }
    float Dval = Dp[d];
    __syncthreads();

#pragma unroll 4
    for (int t = 0; t < CLv; ++t) {
        size_t rA = (size_t)(row0 + t);
        size_t rB = (size_t)(row0 + CLv + t);
        float dl0 = delta[rA * Dm + d], xv0 = x[rA * Dm + d];
        float dl1 = delta[rB * Dm + d], xv1 = x[rB * Dm + d];
        const float* p0 = bcs + t * 32;
        const float* p1 = bcs + (CLv + t) * 32;
        float dx0 = dl0 * xv0, dx1 = dl1 * xv1;
        float y0a[4] = {0.f,0.f,0.f,0.f}, y1a[4] = {0.f,0.f,0.f,0.f};
#pragma unroll
        for (int n = 0; n < Ns; ++n) {
            h0[n] = fmaf(ex2(dl0 * a2[n]), h0[n], dx0 * p0[n]);
            y0a[n & 3] = fmaf(h0[n], p0[16 + n], y0a[n & 3]);
            h1[n] = fmaf(ex2(dl1 * a2[n]), h1[n], dx1 * p1[n]);
            y1a[n & 3] = fmaf(h1[n], p1[16 + n], y1a[n & 3]);
        }
        out[rA * Dm + d] = fmaf(xv0, Dval, (y0a[0] + y0a[1]) + (y0a[2] + y0a[3]));
        out[rB * Dm + d] = fmaf(xv1, Dval, (y1a[0] + y1a[1]) + (y1a[2] + y1a[3]));
    }
}

extern "C" void kernel_launch(void* const* d_in, const int* in_sizes, int n_in,
                              void* d_out, int out_size, void* d_ws, size_t ws_size,
                              hipStream_t stream) {
    const float* x     = (const float*)d_in[0];
    const float* A_log = (const float*)d_in[1];
    const float* Dp    = (const float*)d_in[2];
    const float* xw    = (const float*)d_in[3];
    const float* dtw   = (const float*)d_in[4];
    const float* dtb   = (const float*)d_in[5];
    float* out = (float*)d_out;
    float* ws  = (float*)d_ws;

    // layout (floats):
    //   xp    : 393216
    //   delta : 4194304
    //   S3    : phase 1: xp_part = 8*393216 = 3145728  [dead after k_prep]
    //           phase 3+: Ec | Sc | Hloc | Spre | Eg | Sg | Hg  (CH=128: ~9.45M)
    float* xp      = ws;
    float* delta   = xp + 393216;
    float* S3      = delta + 4194304;
    float* xp_part = S3;

    k_xproj<<<dim3(2048), dim3(NTHR), 0, stream>>>(x, xw, xp_part);
    k_prep <<<dim3(384),  dim3(NTHR), 0, stream>>>(xp_part, xp);
    k_delta<<<dim3(512),  dim3(NTHR), 0, stream>>>(xp, dtw, dtb, delta);

    constexpr int G = 8;
    constexpr int CHv = 128;
    float* Ec   = S3;
    float* Sc   = Ec   + (size_t)Bb*CHv*Dm*Ns;
    float* Hloc = Sc   + (size_t)Bb*CHv*Dm;
    float* Spre = Hloc + (size_t)Bb*CHv*Dm*Ns;
    float* Eg   = Spre + (size_t)Bb*CHv*Dm;
    float* Sg   = Eg   + (size_t)Bb*G*Dm*Ns;
    float* Hg   = Sg   + (size_t)Bb*G*Dm;

    k_scan_part<CHv>  <<<dim3(Bb*(CHv/2)*4), dim3(NTHR), 0, stream>>>(delta, x, xp, A_log, Ec, Sc);
    k_comb1<CHv, G>   <<<dim3(Bb*G*Dm*Ns/NTHR), dim3(NTHR), 0, stream>>>(Ec, Sc, A_log, Hloc, Spre, Eg, Sg);
    k_comb2<G>        <<<dim3(Bb*Dm*Ns/NTHR), dim3(NTHR), 0, stream>>>(Eg, Sg, A_log, Hg);
    k_scan_full<CHv,G><<<dim3(Bb*(CHv/2)*4), dim3(NTHR), 0, stream>>>(delta, x, xp, A_log, Dp, Hloc, Spre, Hg, out);
}